// Round 1
// baseline (3143.186 us; speedup 1.0000x reference)
//
#include <hip/hip_runtime.h>
#include <math.h>

// Problem constants
#define BATCH 2
#define SEQ 2048
#define DMODEL 2048
#define NHEADS 16
#define HEADDIM 128
#define MTOT (BATCH * SEQ)   // 4096

// ---------------------------------------------------------------------------
// GEMM: C[M,N] = A[M,K] * W[N,K]^T   (fp32, 128x128 tile, BK=16, 8x8/thread)
// ---------------------------------------------------------------------------
#define BM 128
#define BN 128
#define BKG 16

__global__ __launch_bounds__(256) void gemm_xwt(const float* __restrict__ A,
                                                const float* __restrict__ W,
                                                float* __restrict__ C,
                                                int M, int N, int K) {
    __shared__ float As[BKG][BM + 4];
    __shared__ float Ws[BKG][BN + 4];

    const int tid = threadIdx.x;
    const int m0 = blockIdx.y * BM;
    const int n0 = blockIdx.x * BN;
    const int r0 = (tid >> 4) * 8;   // 0..120
    const int c0 = (tid & 15) * 8;   // 0..120

    float acc[8][8];
#pragma unroll
    for (int i = 0; i < 8; i++)
#pragma unroll
        for (int j = 0; j < 8; j++) acc[i][j] = 0.f;

    for (int k0 = 0; k0 < K; k0 += BKG) {
        __syncthreads();  // protect LDS from previous iteration's readers
        // stage A tile (128 rows x 16 k) and W tile (128 rows x 16 k)
#pragma unroll
        for (int it = 0; it < 2; it++) {
            int f = tid + 256 * it;          // 0..511 (512 float4 per tile)
            int row = f >> 2;                // 0..127
            int kc = (f & 3) << 2;           // 0,4,8,12
            float4 av = *(const float4*)(A + (size_t)(m0 + row) * K + k0 + kc);
            As[kc + 0][row] = av.x;
            As[kc + 1][row] = av.y;
            As[kc + 2][row] = av.z;
            As[kc + 3][row] = av.w;
            float4 wv = *(const float4*)(W + (size_t)(n0 + row) * K + k0 + kc);
            Ws[kc + 0][row] = wv.x;
            Ws[kc + 1][row] = wv.y;
            Ws[kc + 2][row] = wv.z;
            Ws[kc + 3][row] = wv.w;
        }
        __syncthreads();

#pragma unroll
        for (int kk = 0; kk < BKG; kk++) {
            float a[8], b[8];
            *(float4*)(a + 0) = *(const float4*)&As[kk][r0];
            *(float4*)(a + 4) = *(const float4*)&As[kk][r0 + 4];
            *(float4*)(b + 0) = *(const float4*)&Ws[kk][c0];
            *(float4*)(b + 4) = *(const float4*)&Ws[kk][c0 + 4];
#pragma unroll
            for (int i = 0; i < 8; i++)
#pragma unroll
                for (int j = 0; j < 8; j++) acc[i][j] += a[i] * b[j];
        }
    }

#pragma unroll
    for (int i = 0; i < 8; i++) {
        float4 v0 = make_float4(acc[i][0], acc[i][1], acc[i][2], acc[i][3]);
        float4 v1 = make_float4(acc[i][4], acc[i][5], acc[i][6], acc[i][7]);
        *(float4*)(C + (size_t)(m0 + r0 + i) * N + n0 + c0) = v0;
        *(float4*)(C + (size_t)(m0 + r0 + i) * N + n0 + c0 + 4) = v1;
    }
}

// ---------------------------------------------------------------------------
// RoPE (in-place on [M, D] buffer viewed as [M, H, 128]); pairs (d, d+64)
// ---------------------------------------------------------------------------
__global__ __launch_bounds__(256) void rope_kernel(float* __restrict__ buf) {
    size_t idx = (size_t)blockIdx.x * 256 + threadIdx.x;  // over M*H*64
    int d = (int)(idx & 63);
    int h = (int)((idx >> 6) & (NHEADS - 1));
    int m = (int)(idx >> 10);
    int s = m & (SEQ - 1);  // m = b*SEQ + s
    // inv_freq = 10000^(-d/64) = exp(-d * ln(10000)/64)
    float inv = expf(-(float)d * 0.14391156831212787f);
    float f = (float)s * inv;
    float sn, cs;
    sincosf(f, &sn, &cs);
    size_t base = (size_t)m * DMODEL + h * HEADDIM + d;
    float x1 = buf[base];
    float x2 = buf[base + 64];
    buf[base]      = x1 * cs - x2 * sn;
    buf[base + 64] = x2 * cs + x1 * sn;
}

// ---------------------------------------------------------------------------
// Flash-style causal attention (fp32).
// Q,K,V layout: [B, S, H*128]. grid = (S/32, H, B), 256 threads.
// ---------------------------------------------------------------------------
#define AQ 32
#define AK 32
#define DHP (HEADDIM + 4)

__global__ __launch_bounds__(256) void attn_kernel(const float* __restrict__ Q,
                                                   const float* __restrict__ K,
                                                   const float* __restrict__ V,
                                                   float* __restrict__ O) {
    __shared__ float Qs[AQ][DHP];
    __shared__ float Ks[AK][DHP];
    __shared__ float Vs[AK][DHP];
    __shared__ float Ps[AQ][AK + 1];
    __shared__ float sh_m[AQ], sh_l[AQ], sh_alpha[AQ];

    const int tid = threadIdx.x;
    const int qt = blockIdx.x;
    const int h = blockIdx.y;
    const int b = blockIdx.z;
    const int qbase = qt * AQ;
    const int ty = tid >> 4;   // 0..15
    const int tx = tid & 15;   // 0..15
    const float scale = 0.08838834764831845f;  // 1/sqrt(128)

    const float* Qg = Q + (size_t)b * SEQ * DMODEL + h * HEADDIM;
    const float* Kg = K + (size_t)b * SEQ * DMODEL + h * HEADDIM;
    const float* Vg = V + (size_t)b * SEQ * DMODEL + h * HEADDIM;

    // load Q tile, pre-scaled
#pragma unroll
    for (int it = 0; it < 4; it++) {
        int f = tid + 256 * it;        // 0..1023
        int row = f >> 5;              // 0..31
        int col4 = (f & 31) << 2;      // 0..124
        float4 v = *(const float4*)(Qg + (size_t)(qbase + row) * DMODEL + col4);
        v.x *= scale; v.y *= scale; v.z *= scale; v.w *= scale;
        *(float4*)&Qs[row][col4] = v;
    }
    if (tid < AQ) {
        sh_m[tid] = -1e30f;
        sh_l[tid] = 0.f;
    }

    float o[2][8];
#pragma unroll
    for (int i = 0; i < 2; i++)
#pragma unroll
        for (int j = 0; j < 8; j++) o[i][j] = 0.f;

    for (int kt = 0; kt <= qt; kt++) {
        const int kbase = kt * AK;
        __syncthreads();  // previous iter PV reads done; Q-load visible on iter 0
        // stage K and V tiles
#pragma unroll
        for (int it = 0; it < 4; it++) {
            int f = tid + 256 * it;
            int row = f >> 5;
            int col4 = (f & 31) << 2;
            *(float4*)&Ks[row][col4] =
                *(const float4*)(Kg + (size_t)(kbase + row) * DMODEL + col4);
            *(float4*)&Vs[row][col4] =
                *(const float4*)(Vg + (size_t)(kbase + row) * DMODEL + col4);
        }
        __syncthreads();

        // scores: rows {ty, ty+16} x cols {tx, tx+16}
        float s00 = 0.f, s01 = 0.f, s10 = 0.f, s11 = 0.f;
#pragma unroll
        for (int k = 0; k < HEADDIM; k += 4) {
            float4 q0 = *(const float4*)&Qs[ty][k];
            float4 q1 = *(const float4*)&Qs[ty + 16][k];
            float4 k0 = *(const float4*)&Ks[tx][k];
            float4 k1 = *(const float4*)&Ks[tx + 16][k];
            s00 += q0.x * k0.x + q0.y * k0.y + q0.z * k0.z + q0.w * k0.w;
            s01 += q0.x * k1.x + q0.y * k1.y + q0.z * k1.z + q0.w * k1.w;
            s10 += q1.x * k0.x + q1.y * k0.y + q1.z * k0.z + q1.w * k0.w;
            s11 += q1.x * k1.x + q1.y * k1.y + q1.z * k1.z + q1.w * k1.w;
        }
        // causal mask (keep k <= q), write raw scores
        Ps[ty][tx]           = (kbase + tx      <= qbase + ty)      ? s00 : -1e30f;
        Ps[ty][tx + 16]      = (kbase + tx + 16 <= qbase + ty)      ? s01 : -1e30f;
        Ps[ty + 16][tx]      = (kbase + tx      <= qbase + ty + 16) ? s10 : -1e30f;
        Ps[ty + 16][tx + 16] = (kbase + tx + 16 <= qbase + ty + 16) ? s11 : -1e30f;
        __syncthreads();

        // online softmax row update (one thread per row)
        if (tid < AQ) {
            const int r = tid;
            float mold = sh_m[r];
            float mx = mold;
#pragma unroll
            for (int c = 0; c < AK; c++) mx = fmaxf(mx, Ps[r][c]);
            float alpha = __expf(mold - mx);
            float sum = 0.f;
#pragma unroll
            for (int c = 0; c < AK; c++) {
                float p = __expf(Ps[r][c] - mx);
                Ps[r][c] = p;
                sum += p;
            }
            sh_l[r] = sh_l[r] * alpha + sum;
            sh_m[r] = mx;
            sh_alpha[r] = alpha;
        }
        __syncthreads();

        // O = O*alpha + P*V ; rows {ty, ty+16}, cols [8*tx, 8*tx+8)
        float a0 = sh_alpha[ty], a1 = sh_alpha[ty + 16];
#pragma unroll
        for (int j = 0; j < 8; j++) {
            o[0][j] *= a0;
            o[1][j] *= a1;
        }
#pragma unroll
        for (int c = 0; c < AK; c++) {
            float p0 = Ps[ty][c];
            float p1 = Ps[ty + 16][c];
            float4 v0 = *(const float4*)&Vs[c][8 * tx];
            float4 v1 = *(const float4*)&Vs[c][8 * tx + 4];
            o[0][0] += p0 * v0.x; o[0][1] += p0 * v0.y;
            o[0][2] += p0 * v0.z; o[0][3] += p0 * v0.w;
            o[0][4] += p0 * v1.x; o[0][5] += p0 * v1.y;
            o[0][6] += p0 * v1.z; o[0][7] += p0 * v1.w;
            o[1][0] += p1 * v0.x; o[1][1] += p1 * v0.y;
            o[1][2] += p1 * v0.z; o[1][3] += p1 * v0.w;
            o[1][4] += p1 * v1.x; o[1][5] += p1 * v1.y;
            o[1][6] += p1 * v1.z; o[1][7] += p1 * v1.w;
        }
    }

    // epilogue: normalize and store [B,S,H,128]
    float l0 = 1.f / sh_l[ty];
    float l1 = 1.f / sh_l[ty + 16];
    float* Og = O + (size_t)b * SEQ * DMODEL + h * HEADDIM;
    float4 w0 = make_float4(o[0][0] * l0, o[0][1] * l0, o[0][2] * l0, o[0][3] * l0);
    float4 w1 = make_float4(o[0][4] * l0, o[0][5] * l0, o[0][6] * l0, o[0][7] * l0);
    float4 w2 = make_float4(o[1][0] * l1, o[1][1] * l1, o[1][2] * l1, o[1][3] * l1);
    float4 w3 = make_float4(o[1][4] * l1, o[1][5] * l1, o[1][6] * l1, o[1][7] * l1);
    *(float4*)(Og + (size_t)(qbase + ty) * DMODEL + 8 * tx) = w0;
    *(float4*)(Og + (size_t)(qbase + ty) * DMODEL + 8 * tx + 4) = w1;
    *(float4*)(Og + (size_t)(qbase + ty + 16) * DMODEL + 8 * tx) = w2;
    *(float4*)(Og + (size_t)(qbase + ty + 16) * DMODEL + 8 * tx + 4) = w3;
}

// ---------------------------------------------------------------------------
extern "C" void kernel_launch(void* const* d_in, const int* in_sizes, int n_in,
                              void* d_out, int out_size, void* d_ws, size_t ws_size,
                              hipStream_t stream) {
    const float* query = (const float*)d_in[0];
    const float* Wq = (const float*)d_in[1];
    const float* Wk = (const float*)d_in[2];
    const float* Wv = (const float*)d_in[3];
    const float* Wo = (const float*)d_in[4];
    float* out = (float*)d_out;

    const size_t bufElems = (size_t)MTOT * DMODEL;  // 8,388,608
    float* qbuf = (float*)d_ws;
    float* kbuf = qbuf + bufElems;
    float* vbuf = kbuf + bufElems;
    float* abuf = vbuf + bufElems;

    dim3 gGemm(DMODEL / BN, MTOT / BM);  // (16, 32)

    gemm_xwt<<<gGemm, 256, 0, stream>>>(query, Wq, qbuf, MTOT, DMODEL, DMODEL);
    gemm_xwt<<<gGemm, 256, 0, stream>>>(query, Wk, kbuf, MTOT, DMODEL, DMODEL);
    gemm_xwt<<<gGemm, 256, 0, stream>>>(query, Wv, vbuf, MTOT, DMODEL, DMODEL);

    const int ropeBlocks = (MTOT * NHEADS * 64) / 256;  // 16384
    rope_kernel<<<ropeBlocks, 256, 0, stream>>>(qbuf);
    rope_kernel<<<ropeBlocks, 256, 0, stream>>>(kbuf);

    attn_kernel<<<dim3(SEQ / AQ, NHEADS, BATCH), 256, 0, stream>>>(qbuf, kbuf, vbuf, abuf);

    gemm_xwt<<<gGemm, 256, 0, stream>>>(abuf, Wo, out, MTOT, DMODEL, DMODEL);
}

// Round 2
// 1940.141 us; speedup vs baseline: 1.6201x; 1.6201x over previous
//
#include <hip/hip_runtime.h>
#include <math.h>

// Problem constants
#define BATCH 2
#define SEQ 2048
#define DMODEL 2048
#define NHEADS 16
#define HEADDIM 128
#define MTOT (BATCH * SEQ)   // 4096

typedef __attribute__((ext_vector_type(8))) short short8;   // 8 bf16 (4 VGPRs)
typedef __attribute__((ext_vector_type(4))) float f32x4;    // 4 fp32

__device__ __forceinline__ short f2bf(float x) {
    unsigned u = __float_as_uint(x);
    unsigned r = (u + 0x7fffu + ((u >> 16) & 1u)) >> 16;
    return (short)r;
}

// ---------------------------------------------------------------------------
// GEMM: C[M,N] = A[M,K] * W[N,K]^T   (fp32, 128x128 tile, BK=16, 8x8/thread)
// ---------------------------------------------------------------------------
#define BM 128
#define BN 128
#define BKG 16

__global__ __launch_bounds__(256) void gemm_xwt(const float* __restrict__ A,
                                                const float* __restrict__ W,
                                                float* __restrict__ C,
                                                int M, int N, int K) {
    __shared__ float As[BKG][BM + 4];
    __shared__ float Ws[BKG][BN + 4];

    const int tid = threadIdx.x;
    const int m0 = blockIdx.y * BM;
    const int n0 = blockIdx.x * BN;
    const int r0 = (tid >> 4) * 8;
    const int c0 = (tid & 15) * 8;

    float acc[8][8];
#pragma unroll
    for (int i = 0; i < 8; i++)
#pragma unroll
        for (int j = 0; j < 8; j++) acc[i][j] = 0.f;

    for (int k0 = 0; k0 < K; k0 += BKG) {
        __syncthreads();
#pragma unroll
        for (int it = 0; it < 2; it++) {
            int f = tid + 256 * it;
            int row = f >> 2;
            int kc = (f & 3) << 2;
            float4 av = *(const float4*)(A + (size_t)(m0 + row) * K + k0 + kc);
            As[kc + 0][row] = av.x;
            As[kc + 1][row] = av.y;
            As[kc + 2][row] = av.z;
            As[kc + 3][row] = av.w;
            float4 wv = *(const float4*)(W + (size_t)(n0 + row) * K + k0 + kc);
            Ws[kc + 0][row] = wv.x;
            Ws[kc + 1][row] = wv.y;
            Ws[kc + 2][row] = wv.z;
            Ws[kc + 3][row] = wv.w;
        }
        __syncthreads();

#pragma unroll
        for (int kk = 0; kk < BKG; kk++) {
            float a[8], b[8];
            *(float4*)(a + 0) = *(const float4*)&As[kk][r0];
            *(float4*)(a + 4) = *(const float4*)&As[kk][r0 + 4];
            *(float4*)(b + 0) = *(const float4*)&Ws[kk][c0];
            *(float4*)(b + 4) = *(const float4*)&Ws[kk][c0 + 4];
#pragma unroll
            for (int i = 0; i < 8; i++)
#pragma unroll
                for (int j = 0; j < 8; j++) acc[i][j] += a[i] * b[j];
        }
    }

#pragma unroll
    for (int i = 0; i < 8; i++) {
        float4 v0 = make_float4(acc[i][0], acc[i][1], acc[i][2], acc[i][3]);
        float4 v1 = make_float4(acc[i][4], acc[i][5], acc[i][6], acc[i][7]);
        *(float4*)(C + (size_t)(m0 + r0 + i) * N + n0 + c0) = v0;
        *(float4*)(C + (size_t)(m0 + r0 + i) * N + n0 + c0 + 4) = v1;
    }
}

// ---------------------------------------------------------------------------
// RoPE + fp32->bf16 convert. src: fp32 [M, H*128]; dst: bf16 same layout.
// scale folded in (1/sqrt(128) for Q, 1.0 for K).
// ---------------------------------------------------------------------------
__global__ __launch_bounds__(256) void rope_conv(const float* __restrict__ src,
                                                 short* __restrict__ dst,
                                                 float scale) {
    size_t idx = (size_t)blockIdx.x * 256 + threadIdx.x;  // over M*H*64
    int d = (int)(idx & 63);
    int h = (int)((idx >> 6) & (NHEADS - 1));
    int m = (int)(idx >> 10);
    int s = m & (SEQ - 1);
    float inv = __expf(-(float)d * 0.14391156831212787f);
    float f = (float)s * inv;
    float sn, cs;
    __sincosf(f, &sn, &cs);
    size_t base = (size_t)m * DMODEL + h * HEADDIM + d;
    float x1 = src[base];
    float x2 = src[base + 64];
    dst[base]      = f2bf((x1 * cs - x2 * sn) * scale);
    dst[base + 64] = f2bf((x2 * cs + x1 * sn) * scale);
}

// ---------------------------------------------------------------------------
// V transpose + convert: vbuf fp32 [B*S, H*128] -> vtb bf16 [B,H,128,S]
// grid: (S/64, 4 d-tiles of 32, B*H); block 256
// ---------------------------------------------------------------------------
__global__ __launch_bounds__(256) void conv_v_t(const float* __restrict__ src,
                                                short* __restrict__ dst) {
    __shared__ __align__(16) short T[32][72];
    const int tid = threadIdx.x;
    const int s0 = blockIdx.x * 64;
    const int d0 = blockIdx.y * 32;
    const int bh = blockIdx.z;           // b*16 + h
    const int b = bh >> 4;
    const int h = bh & 15;

    // read 64 s x 32 d fp32 tile (coalesced), write bf16 transposed to LDS
#pragma unroll
    for (int it = 0; it < 2; it++) {
        int f = tid + 256 * it;          // 0..511
        int s = f >> 3;                  // 0..63
        int d4 = (f & 7) * 4;            // 0..28
        float4 v = *(const float4*)(src + (size_t)(b * SEQ + s0 + s) * DMODEL +
                                    h * HEADDIM + d0 + d4);
        T[d4 + 0][s] = f2bf(v.x);
        T[d4 + 1][s] = f2bf(v.y);
        T[d4 + 2][s] = f2bf(v.z);
        T[d4 + 3][s] = f2bf(v.w);
    }
    __syncthreads();

    // write out: 32 d-rows x 64 s (coalesced 16B chunks)
    int row = tid >> 3;                  // 0..31
    int chunk = tid & 7;                 // 0..7
    uint4 val = *(const uint4*)&T[row][chunk * 8];
    *(uint4*)(dst + ((size_t)(bh * HEADDIM + d0 + row)) * SEQ + s0 + chunk * 8) = val;
}

// ---------------------------------------------------------------------------
// Flash causal attention, bf16 MFMA (16x16x32).
// qb, kb: bf16 [B,S,H*128] (q pre-scaled); vtb: bf16 [B,H,128,S].
// O: fp32 [B,S,H*128]. grid (S/64, H, B), 256 threads (4 waves x 16 q rows).
// ---------------------------------------------------------------------------
__global__ __launch_bounds__(256) void attn_mfma(const short* __restrict__ qb,
                                                 const short* __restrict__ kb,
                                                 const short* __restrict__ vtb,
                                                 float* __restrict__ Og) {
    __shared__ __align__(16) short Ks[64][136];    // 64 keys x (128+8)
    __shared__ __align__(16) short Vts[128][72];   // 128 d x (64+8)
    __shared__ __align__(16) short Ps[4][16][72];  // per-wave P: 16 q x (64+8)

    const int tid = threadIdx.x;
    const int wave = tid >> 6;
    const int lane = tid & 63;
    const int quad = lane >> 4;   // 0..3
    const int lcol = lane & 15;   // 0..15

    const int qt = blockIdx.x;
    const int h = blockIdx.y;
    const int b = blockIdx.z;
    const int q0 = qt * 64 + wave * 16;     // wave's q-row base

    // Q fragments (A-layout): lane holds Q[m=lcol][k=quad*8+j], 4 k-steps of 32
    short8 aq[4];
    {
        const short* qrow = qb + (size_t)(b * SEQ + q0 + lcol) * DMODEL + h * HEADDIM;
#pragma unroll
        for (int st = 0; st < 4; st++)
            aq[st] = *(const short8*)(qrow + quad * 8 + 32 * st);
    }

    f32x4 Of[8];
#pragma unroll
    for (int dt = 0; dt < 8; dt++) Of[dt] = (f32x4){0.f, 0.f, 0.f, 0.f};
    float m_r[4], l_r[4];
#pragma unroll
    for (int r = 0; r < 4; r++) { m_r[r] = -1e30f; l_r[r] = 0.f; }

    const int nkt = qt + 1;
    for (int kt = 0; kt < nkt; kt++) {
        const int kbase = kt * 64;
        __syncthreads();
        // stage K tile: 64 rows x 128 bf16 (1024 x 16B chunks)
#pragma unroll
        for (int c = 0; c < 4; c++) {
            int idx = tid + 256 * c;
            int row = idx >> 4;
            int off = (idx & 15) * 8;
            *(uint4*)&Ks[row][off] =
                *(const uint4*)(kb + (size_t)(b * SEQ + kbase + row) * DMODEL +
                                h * HEADDIM + off);
        }
        // stage Vt tile: 128 d-rows x 64 keys
#pragma unroll
        for (int c = 0; c < 4; c++) {
            int idx = tid + 256 * c;
            int row = idx >> 3;
            int off = (idx & 7) * 8;
            *(uint4*)&Vts[row][off] =
                *(const uint4*)(vtb + ((size_t)((b * NHEADS + h) * HEADDIM + row)) * SEQ +
                                kbase + off);
        }
        __syncthreads();

        // S = Q K^T : 4 subtiles of 16 cols, 4 k-steps each
        f32x4 Sc[4];
#pragma unroll
        for (int s = 0; s < 4; s++) {
            Sc[s] = (f32x4){0.f, 0.f, 0.f, 0.f};
#pragma unroll
            for (int st = 0; st < 4; st++) {
                short8 bk = *(const short8*)&Ks[16 * s + lcol][quad * 8 + 32 * st];
                Sc[s] = __builtin_amdgcn_mfma_f32_16x16x32_bf16(aq[st], bk, Sc[s], 0, 0, 0);
            }
        }

        // causal mask on diagonal tile: C layout row = quad*4+r, col = 16*s+lcol
        if (kt == nkt - 1) {
#pragma unroll
            for (int s = 0; s < 4; s++)
#pragma unroll
                for (int r = 0; r < 4; r++)
                    if (kbase + 16 * s + lcol > q0 + quad * 4 + r) Sc[s][r] = -1e30f;
        }

        // online softmax, register-resident (rows live per-quad)
#pragma unroll
        for (int r = 0; r < 4; r++) {
            float mx = fmaxf(fmaxf(Sc[0][r], Sc[1][r]), fmaxf(Sc[2][r], Sc[3][r]));
            mx = fmaxf(mx, __shfl_xor(mx, 1));
            mx = fmaxf(mx, __shfl_xor(mx, 2));
            mx = fmaxf(mx, __shfl_xor(mx, 4));
            mx = fmaxf(mx, __shfl_xor(mx, 8));
            float mnew = fmaxf(m_r[r], mx);
            float alpha = __expf(m_r[r] - mnew);
            m_r[r] = mnew;
            float sum = 0.f;
#pragma unroll
            for (int s = 0; s < 4; s++) {
                float p = __expf(Sc[s][r] - mnew);
                Sc[s][r] = p;
                sum += p;
            }
            sum += __shfl_xor(sum, 1);
            sum += __shfl_xor(sum, 2);
            sum += __shfl_xor(sum, 4);
            sum += __shfl_xor(sum, 8);
            l_r[r] = l_r[r] * alpha + sum;
#pragma unroll
            for (int dt = 0; dt < 8; dt++) Of[dt][r] *= alpha;
        }

        // P -> LDS (bf16) for A-operand relayout
#pragma unroll
        for (int s = 0; s < 4; s++)
#pragma unroll
            for (int r = 0; r < 4; r++)
                Ps[wave][quad * 4 + r][16 * s + lcol] = f2bf(Sc[s][r]);
        __syncthreads();

        // O += P V : A = P (16x64), B = V (64 keys x 16 d-cols) from Vt rows
        short8 ap[2];
#pragma unroll
        for (int st = 0; st < 2; st++)
            ap[st] = *(const short8*)&Ps[wave][lcol][quad * 8 + 32 * st];
#pragma unroll
        for (int dt = 0; dt < 8; dt++) {
#pragma unroll
            for (int st = 0; st < 2; st++) {
                short8 bv = *(const short8*)&Vts[16 * dt + lcol][quad * 8 + 32 * st];
                Of[dt] = __builtin_amdgcn_mfma_f32_16x16x32_bf16(ap[st], bv, Of[dt], 0, 0, 0);
            }
        }
    }

    // epilogue: normalize, store fp32 [B,S,H*128]
    float invl[4];
#pragma unroll
    for (int r = 0; r < 4; r++) invl[r] = 1.f / l_r[r];
    float* obase = Og + (size_t)(b * SEQ + q0 + quad * 4) * DMODEL + h * HEADDIM;
#pragma unroll
    for (int dt = 0; dt < 8; dt++)
#pragma unroll
        for (int r = 0; r < 4; r++)
            obase[(size_t)r * DMODEL + 16 * dt + lcol] = Of[dt][r] * invl[r];
}

// ---------------------------------------------------------------------------
extern "C" void kernel_launch(void* const* d_in, const int* in_sizes, int n_in,
                              void* d_out, int out_size, void* d_ws, size_t ws_size,
                              hipStream_t stream) {
    const float* query = (const float*)d_in[0];
    const float* Wq = (const float*)d_in[1];
    const float* Wk = (const float*)d_in[2];
    const float* Wv = (const float*)d_in[3];
    const float* Wo = (const float*)d_in[4];
    float* out = (float*)d_out;

    const size_t bufElems = (size_t)MTOT * DMODEL;  // 8,388,608 fp32 = 32 MB
    float* ws = (float*)d_ws;
    float* qbuf = ws;                         // [0,32) MB  fp32 Q proj
    float* kbuf = ws + bufElems;              // [32,64) MB fp32 K proj
    float* vbuf = ws + 2 * bufElems;          // [64,96) MB fp32 V proj
    short* qb  = (short*)(ws + 3 * bufElems); // [96,112) MB bf16 Q (rope+scale)
    short* kb  = (short*)ws;                  // [0,16) MB  bf16 K (reuses dead qbuf)
    short* vtb = (short*)(ws + bufElems / 2); // [16,32) MB bf16 V^T (reuses dead qbuf)
    float* abuf = ws + bufElems;              // [32,64) MB fp32 attn out (reuses dead kbuf)

    dim3 gGemm(DMODEL / BN, MTOT / BM);  // (16, 32)

    gemm_xwt<<<gGemm, 256, 0, stream>>>(query, Wq, qbuf, MTOT, DMODEL, DMODEL);
    gemm_xwt<<<gGemm, 256, 0, stream>>>(query, Wk, kbuf, MTOT, DMODEL, DMODEL);
    gemm_xwt<<<gGemm, 256, 0, stream>>>(query, Wv, vbuf, MTOT, DMODEL, DMODEL);

    const int ropeBlocks = (MTOT * NHEADS * 64) / 256;  // 16384
    rope_conv<<<ropeBlocks, 256, 0, stream>>>(qbuf, qb, 0.08838834764831845f);
    rope_conv<<<ropeBlocks, 256, 0, stream>>>(kbuf, kb, 1.0f);
    conv_v_t<<<dim3(SEQ / 64, HEADDIM / 32, BATCH * NHEADS), 256, 0, stream>>>(vbuf, vtb);

    attn_mfma<<<dim3(SEQ / 64, NHEADS, BATCH), 256, 0, stream>>>(qb, kb, vtb, abuf);

    gemm_xwt<<<gGemm, 256, 0, stream>>>(abuf, Wo, out, MTOT, DMODEL, DMODEL);
}

// Round 3
// 564.263 us; speedup vs baseline: 5.5704x; 3.4384x over previous
//
#include <hip/hip_runtime.h>
#include <math.h>

// Problem constants
#define BATCH 2
#define SEQ 2048
#define DMODEL 2048
#define NHEADS 16
#define HEADDIM 128
#define MTOT (BATCH * SEQ)   // 4096

typedef __attribute__((ext_vector_type(8))) _Float16 half8;  // 8 f16 (4 VGPRs)
typedef __attribute__((ext_vector_type(4))) float f32x4;     // 4 fp32

// async global -> LDS, 16B per lane (global_load_lds_dwordx4)
__device__ __forceinline__ void gl_lds16(const void* g, void* l) {
    __builtin_amdgcn_global_load_lds(
        (const __attribute__((address_space(1))) unsigned int*)g,
        (__attribute__((address_space(3))) unsigned int*)l, 16, 0, 0);
}

// ---------------------------------------------------------------------------
// fp32 -> f16 elementwise convert, 8 elems/thread
// ---------------------------------------------------------------------------
__global__ __launch_bounds__(256) void f2h_conv(const float* __restrict__ src,
                                                _Float16* __restrict__ dst) {
    size_t i = ((size_t)blockIdx.x * 256 + threadIdx.x) * 8;
    float4 a = *(const float4*)(src + i);
    float4 b = *(const float4*)(src + i + 4);
    union { uint4 u; _Float16 h[8]; } o;
    o.h[0] = (_Float16)a.x; o.h[1] = (_Float16)a.y;
    o.h[2] = (_Float16)a.z; o.h[3] = (_Float16)a.w;
    o.h[4] = (_Float16)b.x; o.h[5] = (_Float16)b.y;
    o.h[6] = (_Float16)b.z; o.h[7] = (_Float16)b.w;
    *(uint4*)(dst + i) = o.u;
}

// ---------------------------------------------------------------------------
// f16 MFMA GEMM: C[M,N] = A[M,K] * W[N,K]^T
// 128x128 tile, BK=32, global_load_lds staging, 4 waves x (4x4) 16x16x32 MFMA
// ---------------------------------------------------------------------------
template <bool F16OUT>
__global__ __launch_bounds__(256) void gemm_h(const _Float16* __restrict__ A,
                                              const _Float16* __restrict__ W,
                                              void* __restrict__ Cout,
                                              int M, int N, int K) {
    __shared__ __align__(16) _Float16 As[128 * 32];  // 8 KB, row-major [m][k]
    __shared__ __align__(16) _Float16 Bs[128 * 32];  // 8 KB, row-major [n][k]

    const int tid = threadIdx.x;
    const int wv = tid >> 6;
    const int ln = tid & 63;
    const int quad = ln >> 4;   // 0..3
    const int lcol = ln & 15;   // 0..15
    const int m0 = blockIdx.y * 128;
    const int n0 = blockIdx.x * 128;
    const int wm = (wv >> 1) * 64;   // wave quadrant
    const int wn = (wv & 1) * 64;

    const int srow = ln >> 2;        // 0..15 row within staging instr
    const int kblk = (ln & 3) * 8;   // 0,8,16,24 (f16 elems)

    f32x4 acc[4][4];
#pragma unroll
    for (int i = 0; i < 4; i++)
#pragma unroll
        for (int j = 0; j < 4; j++) acc[i][j] = (f32x4){0.f, 0.f, 0.f, 0.f};

    for (int k0 = 0; k0 < K; k0 += 32) {
        __syncthreads();
        // stage A-tile (128x32) and B-tile (128x32); wave wv covers rows wv*32..+31
#pragma unroll
        for (int j = 0; j < 2; j++) {
            int r = wv * 32 + j * 16 + srow;
            gl_lds16(A + (size_t)(m0 + r) * K + k0 + kblk, &As[r * 32 + kblk]);
            gl_lds16(W + (size_t)(n0 + r) * K + k0 + kblk, &Bs[r * 32 + kblk]);
        }
        __syncthreads();

        half8 af[4], bf[4];
#pragma unroll
        for (int ms = 0; ms < 4; ms++)
            af[ms] = *(const half8*)&As[(wm + ms * 16 + lcol) * 32 + quad * 8];
#pragma unroll
        for (int ns = 0; ns < 4; ns++)
            bf[ns] = *(const half8*)&Bs[(wn + ns * 16 + lcol) * 32 + quad * 8];
#pragma unroll
        for (int ms = 0; ms < 4; ms++)
#pragma unroll
            for (int ns = 0; ns < 4; ns++)
                acc[ms][ns] = __builtin_amdgcn_mfma_f32_16x16x32_f16(
                    af[ms], bf[ns], acc[ms][ns], 0, 0, 0);
    }

    // epilogue: C layout row = quad*4+r, col = lcol (per 16x16 subtile)
    float* Cf = (float*)Cout;
    _Float16* Ch = (_Float16*)Cout;
#pragma unroll
    for (int ms = 0; ms < 4; ms++)
#pragma unroll
        for (int ns = 0; ns < 4; ns++)
#pragma unroll
            for (int r = 0; r < 4; r++) {
                size_t row = m0 + wm + ms * 16 + quad * 4 + r;
                size_t col = n0 + wn + ns * 16 + lcol;
                if (F16OUT)
                    Ch[row * N + col] = (_Float16)acc[ms][ns][r];
                else
                    Cf[row * N + col] = acc[ms][ns][r];
            }
}

// ---------------------------------------------------------------------------
// RoPE in-place on f16 [M, H*128]; pairs (d, d+64); scale folded in
// ---------------------------------------------------------------------------
__global__ __launch_bounds__(256) void rope_h(_Float16* __restrict__ buf, float scale) {
    size_t idx = (size_t)blockIdx.x * 256 + threadIdx.x;  // over M*H*64
    int d = (int)(idx & 63);
    int h = (int)((idx >> 6) & (NHEADS - 1));
    int m = (int)(idx >> 10);
    int s = m & (SEQ - 1);
    float inv = __expf(-(float)d * 0.14391156831212787f);
    float f = (float)s * inv;
    float sn, cs;
    __sincosf(f, &sn, &cs);
    size_t base = (size_t)m * DMODEL + h * HEADDIM + d;
    float x1 = (float)buf[base];
    float x2 = (float)buf[base + 64];
    buf[base]      = (_Float16)((x1 * cs - x2 * sn) * scale);
    buf[base + 64] = (_Float16)((x2 * cs + x1 * sn) * scale);
}

// ---------------------------------------------------------------------------
// V transpose: vh f16 [B*S, H*128] -> vtb f16 [B,H,128,S]
// grid: (S/64, 4 d-tiles of 32, B*H); block 256
// ---------------------------------------------------------------------------
__global__ __launch_bounds__(256) void conv_v_t(const _Float16* __restrict__ src,
                                                _Float16* __restrict__ dst) {
    __shared__ __align__(16) _Float16 T[32][72];
    const int tid = threadIdx.x;
    const int s0 = blockIdx.x * 64;
    const int d0 = blockIdx.y * 32;
    const int bh = blockIdx.z;
    const int b = bh >> 4;
    const int h = bh & 15;

    // read 64 s x 32 d tile: each thread one uint4 (8 f16 along d)
    {
        int s = tid >> 2;             // 0..63
        int d8 = (tid & 3) * 8;       // 0,8,16,24
        union { uint4 u; _Float16 hh[8]; } v;
        v.u = *(const uint4*)(src + (size_t)(b * SEQ + s0 + s) * DMODEL +
                              h * HEADDIM + d0 + d8);
#pragma unroll
        for (int j = 0; j < 8; j++) T[d8 + j][s] = v.hh[j];
    }
    __syncthreads();

    // write out: 32 d-rows x 64 s, one uint4 per thread
    int row = tid >> 3;               // 0..31
    int chunk = tid & 7;              // 0..7
    uint4 val = *(const uint4*)&T[row][chunk * 8];
    *(uint4*)(dst + ((size_t)(bh * HEADDIM + d0 + row)) * SEQ + s0 + chunk * 8) = val;
}

// ---------------------------------------------------------------------------
// Flash causal attention, f16 MFMA (16x16x32).
// qh, kh: f16 [B,S,H*128] (q pre-scaled); vtb: f16 [B,H,128,S].
// Output ab: f16 [B,S,H*128]. grid (S/64, H, B), 256 threads.
// ---------------------------------------------------------------------------
__global__ __launch_bounds__(256) void attn_mfma(const _Float16* __restrict__ qh,
                                                 const _Float16* __restrict__ kh,
                                                 const _Float16* __restrict__ vtb,
                                                 _Float16* __restrict__ ab) {
    __shared__ __align__(16) _Float16 Ks[64][136];
    __shared__ __align__(16) _Float16 Vts[128][72];
    __shared__ __align__(16) _Float16 Ps[4][16][72];

    const int tid = threadIdx.x;
    const int wave = tid >> 6;
    const int lane = tid & 63;
    const int quad = lane >> 4;
    const int lcol = lane & 15;

    const int qt = blockIdx.x;
    const int h = blockIdx.y;
    const int b = blockIdx.z;
    const int q0 = qt * 64 + wave * 16;

    half8 aq[4];
    {
        const _Float16* qrow = qh + (size_t)(b * SEQ + q0 + lcol) * DMODEL + h * HEADDIM;
#pragma unroll
        for (int st = 0; st < 4; st++)
            aq[st] = *(const half8*)(qrow + quad * 8 + 32 * st);
    }

    f32x4 Of[8];
#pragma unroll
    for (int dt = 0; dt < 8; dt++) Of[dt] = (f32x4){0.f, 0.f, 0.f, 0.f};
    float m_r[4], l_r[4];
#pragma unroll
    for (int r = 0; r < 4; r++) { m_r[r] = -1e30f; l_r[r] = 0.f; }

    const int nkt = qt + 1;
    for (int kt = 0; kt < nkt; kt++) {
        const int kbase = kt * 64;
        __syncthreads();
#pragma unroll
        for (int c = 0; c < 4; c++) {
            int idx = tid + 256 * c;
            int row = idx >> 4;
            int off = (idx & 15) * 8;
            *(uint4*)&Ks[row][off] =
                *(const uint4*)(kh + (size_t)(b * SEQ + kbase + row) * DMODEL +
                                h * HEADDIM + off);
        }
#pragma unroll
        for (int c = 0; c < 4; c++) {
            int idx = tid + 256 * c;
            int row = idx >> 3;
            int off = (idx & 7) * 8;
            *(uint4*)&Vts[row][off] =
                *(const uint4*)(vtb + ((size_t)((b * NHEADS + h) * HEADDIM + row)) * SEQ +
                                kbase + off);
        }
        __syncthreads();

        f32x4 Sc[4];
#pragma unroll
        for (int s = 0; s < 4; s++) {
            Sc[s] = (f32x4){0.f, 0.f, 0.f, 0.f};
#pragma unroll
            for (int st = 0; st < 4; st++) {
                half8 bk = *(const half8*)&Ks[16 * s + lcol][quad * 8 + 32 * st];
                Sc[s] = __builtin_amdgcn_mfma_f32_16x16x32_f16(aq[st], bk, Sc[s], 0, 0, 0);
            }
        }

        if (kt == nkt - 1) {
#pragma unroll
            for (int s = 0; s < 4; s++)
#pragma unroll
                for (int r = 0; r < 4; r++)
                    if (kbase + 16 * s + lcol > q0 + quad * 4 + r) Sc[s][r] = -1e30f;
        }

#pragma unroll
        for (int r = 0; r < 4; r++) {
            float mx = fmaxf(fmaxf(Sc[0][r], Sc[1][r]), fmaxf(Sc[2][r], Sc[3][r]));
            mx = fmaxf(mx, __shfl_xor(mx, 1));
            mx = fmaxf(mx, __shfl_xor(mx, 2));
            mx = fmaxf(mx, __shfl_xor(mx, 4));
            mx = fmaxf(mx, __shfl_xor(mx, 8));
            float mnew = fmaxf(m_r[r], mx);
            float alpha = __expf(m_r[r] - mnew);
            m_r[r] = mnew;
            float sum = 0.f;
#pragma unroll
            for (int s = 0; s < 4; s++) {
                float p = __expf(Sc[s][r] - mnew);
                Sc[s][r] = p;
                sum += p;
            }
            sum += __shfl_xor(sum, 1);
            sum += __shfl_xor(sum, 2);
            sum += __shfl_xor(sum, 4);
            sum += __shfl_xor(sum, 8);
            l_r[r] = l_r[r] * alpha + sum;
#pragma unroll
            for (int dt = 0; dt < 8; dt++) Of[dt][r] *= alpha;
        }

#pragma unroll
        for (int s = 0; s < 4; s++)
#pragma unroll
            for (int r = 0; r < 4; r++)
                Ps[wave][quad * 4 + r][16 * s + lcol] = (_Float16)Sc[s][r];
        __syncthreads();

        half8 ap[2];
#pragma unroll
        for (int st = 0; st < 2; st++)
            ap[st] = *(const half8*)&Ps[wave][lcol][quad * 8 + 32 * st];
#pragma unroll
        for (int dt = 0; dt < 8; dt++) {
#pragma unroll
            for (int st = 0; st < 2; st++) {
                half8 bv = *(const half8*)&Vts[16 * dt + lcol][quad * 8 + 32 * st];
                Of[dt] = __builtin_amdgcn_mfma_f32_16x16x32_f16(ap[st], bv, Of[dt], 0, 0, 0);
            }
        }
    }

    float invl[4];
#pragma unroll
    for (int r = 0; r < 4; r++) invl[r] = 1.f / l_r[r];
    _Float16* obase = ab + (size_t)(b * SEQ + q0 + quad * 4) * DMODEL + h * HEADDIM;
#pragma unroll
    for (int dt = 0; dt < 8; dt++)
#pragma unroll
        for (int r = 0; r < 4; r++)
            obase[(size_t)r * DMODEL + 16 * dt + lcol] = (_Float16)(Of[dt][r] * invl[r]);
}

// ---------------------------------------------------------------------------
extern "C" void kernel_launch(void* const* d_in, const int* in_sizes, int n_in,
                              void* d_out, int out_size, void* d_ws, size_t ws_size,
                              hipStream_t stream) {
    const float* query = (const float*)d_in[0];
    const float* Wq = (const float*)d_in[1];
    const float* Wk = (const float*)d_in[2];
    const float* Wv = (const float*)d_in[3];
    const float* Wo = (const float*)d_in[4];
    float* out = (float*)d_out;

    const size_t MB = 1024 * 1024;
    char* w = (char*)d_ws;
    _Float16* xh  = (_Float16*)(w + 0 * MB);    // 16 MB f16 query
    _Float16* qh  = (_Float16*)(w + 16 * MB);   // 16 MB f16 Q proj (rope'd, scaled)
    _Float16* kh  = (_Float16*)(w + 32 * MB);   // 16 MB f16 K proj (rope'd)
    _Float16* vh  = (_Float16*)(w + 48 * MB);   // 16 MB f16 V proj
    _Float16* vtb = (_Float16*)(w + 64 * MB);   // 16 MB f16 V^T [B,H,128,S]
    _Float16* ab  = (_Float16*)(w + 80 * MB);   // 16 MB f16 attn out
    _Float16* Wh  = (_Float16*)(w + 96 * MB);   // 8 MB  f16 weight slot (reused 4x)

    dim3 gGemm(DMODEL / 128, MTOT / 128);  // (16, 32)
    const int convX = (MTOT * DMODEL) / (256 * 8);     // 4096 blocks
    const int convW = (DMODEL * DMODEL) / (256 * 8);   // 2048 blocks
    const int ropeBlocks = (MTOT * NHEADS * 64) / 256; // 16384

    f2h_conv<<<convX, 256, 0, stream>>>(query, xh);

    f2h_conv<<<convW, 256, 0, stream>>>(Wq, Wh);
    gemm_h<true><<<gGemm, 256, 0, stream>>>(xh, Wh, qh, MTOT, DMODEL, DMODEL);
    f2h_conv<<<convW, 256, 0, stream>>>(Wk, Wh);
    gemm_h<true><<<gGemm, 256, 0, stream>>>(xh, Wh, kh, MTOT, DMODEL, DMODEL);
    f2h_conv<<<convW, 256, 0, stream>>>(Wv, Wh);
    gemm_h<true><<<gGemm, 256, 0, stream>>>(xh, Wh, vh, MTOT, DMODEL, DMODEL);

    rope_h<<<ropeBlocks, 256, 0, stream>>>(qh, 0.08838834764831845f);
    rope_h<<<ropeBlocks, 256, 0, stream>>>(kh, 1.0f);
    conv_v_t<<<dim3(SEQ / 64, HEADDIM / 32, BATCH * NHEADS), 256, 0, stream>>>(vh, vtb);

    attn_mfma<<<dim3(SEQ / 64, NHEADS, BATCH), 256, 0, stream>>>(qh, kh, vtb, ab);

    f2h_conv<<<convW, 256, 0, stream>>>(Wo, Wh);
    gemm_h<false><<<gGemm, 256, 0, stream>>>(ab, Wh, out, MTOT, DMODEL, DMODEL);
}